// Round 7
// baseline (237.856 us; speedup 1.0000x reference)
//
#include <hip/hip_runtime.h>

// Problem constants (x: (16,3,512,512) f32, PATCH=16, STRIDE=8, k=8)
#define BB      16
#define CH      3
#define HH      512
#define WW      512
#define NH      63
#define NW      63
#define NN      3969            // NH*NW
#define FDIM    768             // CH*16*16
#define EDGES   31752           // NN*8

#define PATCHES_ELEMS  (BB * NN * FDIM)   // 48771072
#define POS_ELEMS      (BB * NN * 2)      // 127008

#define PE_THREADS   (BB * NN)            // 63504
#define PE_BLOCKS    256                  // padded to a multiple of 8 so patch
                                          // block p sits at raw index 256+p ->
                                          // XCD = p & 7 (round-robin)
#define PATCH_BLOCKS (BB * NH * CH)       // 3024: one block per (b,i,c)
#define CHUNK        (PATCH_BLOCKS / 8)   // 378 blocks per XCD, exact

typedef float  f4 __attribute__((ext_vector_type(4)));
typedef float  f2 __attribute__((ext_vector_type(2)));

// ---------------------------------------------------------------------------
// Fused kernel.
//  blocks [0, 256): one thread per (b,n) -> positions + 8-NN edges
//    (blocks 249..255 are XCD-alignment padding, exit immediately).
//  blocks [256, +3024): block = one (b, i, c), XCD-chunk-swizzled:
//    p & 7 is the XCD; orig = (p&7)*CHUNK + (p>>3) walks (c fastest, i next,
//    b slowest) so adjacent-i blocks -- which share 8 of their 16 staged
//    input rows (16KB) -- run on the SAME XCD ~3 slots apart and the overlap
//    re-read hits that XCD's 4MB L2 instead of HBM.
//    Stage: 16 adjacent full-width rows = contiguous 32KB -> linear LDS dest
//    -> async global_load_lds(16B) DMA. Write: 64 lanes x 16B = 1KB
//    contiguous nt stores (full lines, no RMW, L2 stays clean for reads).
// ---------------------------------------------------------------------------
__global__ __launch_bounds__(256) void fused_kernel(const float* __restrict__ x,
                                                    float* __restrict__ out) {
    unsigned bid = blockIdx.x;

    if (bid >= PE_BLOCKS) {
        unsigned p    = bid - PE_BLOCKS;            // [0, 3024)
        unsigned orig = (p & 7u) * CHUNK + (p >> 3);// XCD-contiguous chunks
        unsigned c  = orig % CH;
        unsigned bi = orig / CH;
        unsigned i  = bi % NH;
        unsigned b  = bi / NH;
        unsigned tid = threadIdx.x;

        __shared__ float lds[16 * 512];     // 32 KB, linear (row di = 512 floats)

        const float* base = x + ((size_t)(b * CH + c) * HH + i * 8u) * WW;

        // async stage: 8 x global_load_lds(16B) per thread, linear LDS dest
        typedef const __attribute__((address_space(1))) void* gas_p;
        typedef __attribute__((address_space(3))) void*       las_p;
#pragma unroll
        for (unsigned u = 0; u < 8; ++u) {
            unsigned f4id = u * 256u + tid;            // [0, 2048)
            __builtin_amdgcn_global_load_lds((gas_p)(const void*)(base + f4id * 4u),
                                             (las_p)(void*)(lds + f4id * 4u),
                                             16, 0, 0);
        }
        __syncthreads();   // compiler emits vmcnt(0) drain before barrier

        unsigned lane = tid & 63u;
        unsigned wave = tid >> 6;           // 0..3
        unsigned row  = (lane >> 2) << 9;   // di*512
        unsigned coff = (lane & 3u) << 2;   // dj offset 0,4,8,12
        float* obase = out + ((size_t)(b * NN + i * NW) * FDIM) + c * 256u + (lane << 2);

#pragma unroll
        for (unsigned jj = 0; jj < 16; ++jj) {
            unsigned j = jj * 4u + wave;    // wave-strided patches
            if (j < NW) {
                const f4 v = *reinterpret_cast<const f4*>(lds + row + j * 8u + coff);
                __builtin_nontemporal_store(
                    v, reinterpret_cast<f4*>(obase + (size_t)j * FDIM));
            }
        }
    } else {
        unsigned g = bid * 256u + threadIdx.x;
        if (g >= PE_THREADS) return;        // includes padding blocks 249..255
        unsigned n = g % NN;                // lanes contiguous in n
        unsigned b = g / NN;
        int i = (int)(n / NW);
        int j = (int)(n - (unsigned)i * NW);

        // positions
        *reinterpret_cast<f2*>(out + PATCHES_ELEMS + (size_t)(b * NN + n) * 2) =
            f2{(float)i, (float)j};

        // 8-NN on the 63x63 grid: the 9 best (incl. self) of top_k(-d2, 9)
        // always lie in the clipped 5x5 window; key = (d2<<12)|idx reproduces
        // top_k's exact ordering (ties -> lower index).
        unsigned best[9];
#pragma unroll
        for (int s = 0; s < 9; ++s) best[s] = 0xFFFFFFFFu;
        for (int di = -2; di <= 2; ++di) {
            int ni = i + di;
            if (ni < 0 || ni >= NH) continue;
            for (int dj = -2; dj <= 2; ++dj) {
                int nj = j + dj;
                if (nj < 0 || nj >= NW) continue;
                unsigned key = ((unsigned)(di * di + dj * dj) << 12)
                             | (unsigned)(ni * NW + nj);
#pragma unroll
                for (int s = 0; s < 9; ++s) {
                    if (key < best[s]) { unsigned tmp = best[s]; best[s] = key; key = tmp; }
                }
            }
        }

        float src_f = (float)n;
        f4 s4 = {src_f, src_f, src_f, src_f};
        f4 t0 = {(float)(best[1] & 0xFFFu), (float)(best[2] & 0xFFFu),
                 (float)(best[3] & 0xFFFu), (float)(best[4] & 0xFFFu)};
        f4 t1 = {(float)(best[5] & 0xFFFu), (float)(best[6] & 0xFFFu),
                 (float)(best[7] & 0xFFFu), (float)(best[8] & 0xFFFu)};

        float* ebase = out + PATCHES_ELEMS + POS_ELEMS + (size_t)b * 2 * EDGES;
        *reinterpret_cast<f4*>(ebase + (size_t)n * 8)             = s4;
        *reinterpret_cast<f4*>(ebase + (size_t)n * 8 + 4)         = s4;
        *reinterpret_cast<f4*>(ebase + EDGES + (size_t)n * 8)     = t0;
        *reinterpret_cast<f4*>(ebase + EDGES + (size_t)n * 8 + 4) = t1;
    }
}

extern "C" void kernel_launch(void* const* d_in, const int* in_sizes, int n_in,
                              void* d_out, int out_size, void* d_ws, size_t ws_size,
                              hipStream_t stream) {
    const float* x = (const float*)d_in[0];
    float* out     = (float*)d_out;
    fused_kernel<<<PE_BLOCKS + PATCH_BLOCKS, 256, 0, stream>>>(x, out);
}

// Round 8
// 236.139 us; speedup vs baseline: 1.0073x; 1.0073x over previous
//
#include <hip/hip_runtime.h>

// Problem constants (x: (16,3,512,512) f32, PATCH=16, STRIDE=8, k=8)
#define BB      16
#define CH      3
#define HH      512
#define WW      512
#define NH      63
#define NW      63
#define NN      3969            // NH*NW
#define FDIM    768             // CH*16*16
#define EDGES   31752           // NN*8

#define PATCHES_ELEMS  (BB * NN * FDIM)   // 48771072
#define POS_ELEMS      (BB * NN * 2)      // 127008

#define PE_THREADS   (BB * NN)                   // 63504
#define PE_BLOCKS    ((PE_THREADS + 255) / 256)  // 249
#define PATCH_BLOCKS (BB * NH * CH)              // 3024: one block per (b,i,c)

typedef float  f4 __attribute__((ext_vector_type(4)));
typedef float  f2 __attribute__((ext_vector_type(2)));

// ---------------------------------------------------------------------------
// Fused kernel. (Round 8: XCD swizzle reverted — input is L3-fit, swizzle
// cost 2%. Stores switched nontemporal -> cached: nt bypassed L2 and hit the
// MC as thousands of interleaved 1KB@3KB-stride streams (HBM row thrash);
// cached full-line stores aggregate in each XCD's 4MB L2 and write back as
// large bursts, like the 6.6TB/s fill kernel. Input-row reuse window is
// ~200KB << 4MB L2, so no eviction risk.)
//  blocks [0, PE_BLOCKS): one thread per (b,n) -> positions + 8-NN edges.
//  blocks [PE_BLOCKS, +PATCH_BLOCKS): block = one (b, i, c).
//    Stage: 16 adjacent full-width rows = contiguous 32KB -> linear LDS dest
//    -> async global_load_lds(16B) DMA (no VGPR round-trip). 5 blocks/CU;
//    neighbor blocks' store phases hide each other's stage drain.
//    Write: per wave-instr, 64 lanes x 16B = 1KB contiguous (full 64B lines).
// ---------------------------------------------------------------------------
__global__ __launch_bounds__(256) void fused_kernel(const float* __restrict__ x,
                                                    float* __restrict__ out) {
    unsigned bid = blockIdx.x;

    if (bid >= PE_BLOCKS) {
        unsigned pb = bid - PE_BLOCKS;      // [0, 3024)
        unsigned c  = pb % CH;
        unsigned bi = pb / CH;
        unsigned i  = bi % NH;
        unsigned b  = bi / NH;
        unsigned tid = threadIdx.x;

        __shared__ float lds[16 * 512];     // 32 KB, linear (row di = 512 floats)

        const float* base = x + ((size_t)(b * CH + c) * HH + i * 8u) * WW;

        // async stage: 8 x global_load_lds(16B) per thread, linear LDS dest
        typedef const __attribute__((address_space(1))) void* gas_p;
        typedef __attribute__((address_space(3))) void*       las_p;
#pragma unroll
        for (unsigned u = 0; u < 8; ++u) {
            unsigned f4id = u * 256u + tid;            // [0, 2048)
            __builtin_amdgcn_global_load_lds((gas_p)(const void*)(base + f4id * 4u),
                                             (las_p)(void*)(lds + f4id * 4u),
                                             16, 0, 0);
        }
        __syncthreads();   // compiler emits vmcnt(0) drain before barrier

        unsigned lane = tid & 63u;
        unsigned wave = tid >> 6;           // 0..3
        unsigned row  = (lane >> 2) << 9;   // di*512
        unsigned coff = (lane & 3u) << 2;   // dj offset 0,4,8,12
        float* obase = out + ((size_t)(b * NN + i * NW) * FDIM) + c * 256u + (lane << 2);

#pragma unroll
        for (unsigned jj = 0; jj < 16; ++jj) {
            unsigned j = jj * 4u + wave;    // wave-strided patches
            if (j < NW) {
                const f4 v = *reinterpret_cast<const f4*>(lds + row + j * 8u + coff);
                *reinterpret_cast<f4*>(obase + (size_t)j * FDIM) = v;
            }
        }
    } else {
        unsigned g = bid * 256u + threadIdx.x;
        if (g >= PE_THREADS) return;
        unsigned n = g % NN;                // lanes contiguous in n
        unsigned b = g / NN;
        int i = (int)(n / NW);
        int j = (int)(n - (unsigned)i * NW);

        // positions
        *reinterpret_cast<f2*>(out + PATCHES_ELEMS + (size_t)(b * NN + n) * 2) =
            f2{(float)i, (float)j};

        // 8-NN on the 63x63 grid: the 9 best (incl. self) of top_k(-d2, 9)
        // always lie in the clipped 5x5 window; key = (d2<<12)|idx reproduces
        // top_k's exact ordering (ties -> lower index).
        unsigned best[9];
#pragma unroll
        for (int s = 0; s < 9; ++s) best[s] = 0xFFFFFFFFu;
        for (int di = -2; di <= 2; ++di) {
            int ni = i + di;
            if (ni < 0 || ni >= NH) continue;
            for (int dj = -2; dj <= 2; ++dj) {
                int nj = j + dj;
                if (nj < 0 || nj >= NW) continue;
                unsigned key = ((unsigned)(di * di + dj * dj) << 12)
                             | (unsigned)(ni * NW + nj);
#pragma unroll
                for (int s = 0; s < 9; ++s) {
                    if (key < best[s]) { unsigned tmp = best[s]; best[s] = key; key = tmp; }
                }
            }
        }

        float src_f = (float)n;
        f4 s4 = {src_f, src_f, src_f, src_f};
        f4 t0 = {(float)(best[1] & 0xFFFu), (float)(best[2] & 0xFFFu),
                 (float)(best[3] & 0xFFFu), (float)(best[4] & 0xFFFu)};
        f4 t1 = {(float)(best[5] & 0xFFFu), (float)(best[6] & 0xFFFu),
                 (float)(best[7] & 0xFFFu), (float)(best[8] & 0xFFFu)};

        float* ebase = out + PATCHES_ELEMS + POS_ELEMS + (size_t)b * 2 * EDGES;
        *reinterpret_cast<f4*>(ebase + (size_t)n * 8)             = s4;
        *reinterpret_cast<f4*>(ebase + (size_t)n * 8 + 4)         = s4;
        *reinterpret_cast<f4*>(ebase + EDGES + (size_t)n * 8)     = t0;
        *reinterpret_cast<f4*>(ebase + EDGES + (size_t)n * 8 + 4) = t1;
    }
}

extern "C" void kernel_launch(void* const* d_in, const int* in_sizes, int n_in,
                              void* d_out, int out_size, void* d_ws, size_t ws_size,
                              hipStream_t stream) {
    const float* x = (const float*)d_in[0];
    float* out     = (float*)d_out;
    fused_kernel<<<PE_BLOCKS + PATCH_BLOCKS, 256, 0, stream>>>(x, out);
}

// Round 9
// 235.440 us; speedup vs baseline: 1.0103x; 1.0030x over previous
//
#include <hip/hip_runtime.h>

// Problem constants (x: (16,3,512,512) f32, PATCH=16, STRIDE=8, k=8)
#define BB      16
#define CH      3
#define HH      512
#define WW      512
#define NH      63
#define NW      63
#define NN      3969            // NH*NW
#define FDIM    768             // CH*16*16
#define EDGES   31752           // NN*8

#define PATCHES_ELEMS  (BB * NN * FDIM)   // 48771072
#define POS_ELEMS      (BB * NN * 2)      // 127008

#define PE_THREADS   (BB * NN)                   // 63504
#define PE_BLOCKS    ((PE_THREADS + 255) / 256)  // 249
#define NJQ          4                           // j-quarters of 16 (last 15)
#define PATCH_BLOCKS (BB * NH * NJQ)             // 4032: block = (b, i, jq)

// LDS: [48 rows (c*16+di)][136 cols] f32, stride 34 f4 (uniform mod-8 bank
// groups -> near-conflict-free b128 reads). 1632 real f4-slots, padded to
// 1792 (7 x 256) so the staging loop has no divergence. 28672 B -> 5 blk/CU.
#define ROWF4   34
#define SLOTS   1632
#define SLOTS_P 1792

typedef float  f4 __attribute__((ext_vector_type(4)));
typedef float  f2 __attribute__((ext_vector_type(2)));

// ---------------------------------------------------------------------------
// Round 9: write-contiguous patch blocks.
//  blocks [0, PE_BLOCKS): one thread per (b,n) -> positions + 8-NN edges.
//  blocks [PE_BLOCKS, +PATCH_BLOCKS): block = (b, i, jq) produces the FULL
//    768-float patches for 16 consecutive j -> one dense, hole-free 48KB
//    output run per block (vs r5-r8: 1KB pieces at 3KB stride from 3 blocks
//    on different XCDs = DRAM page thrash). Stage: 3ch x 16 rows x 136-col
//    window -> linear LDS via async global_load_lds(16B) with per-lane
//    global srcs. Write: 12 x (64 lanes x 16B = 1KB) nt stores walking the
//    48KB range linearly.
// ---------------------------------------------------------------------------
__global__ __launch_bounds__(256) void fused_kernel(const float* __restrict__ x,
                                                    float* __restrict__ out) {
    unsigned bid = blockIdx.x;

    if (bid >= PE_BLOCKS) {
        unsigned pb = bid - PE_BLOCKS;      // [0, 4032)
        unsigned jq = pb & 3u;
        unsigned bi = pb >> 2;
        unsigned i  = bi % NH;
        unsigned b  = bi / NH;
        unsigned tid = threadIdx.x;

        __shared__ float lds[SLOTS_P * 4];  // 28 KB linear

        typedef const __attribute__((address_space(1))) void* gas_p;
        typedef __attribute__((address_space(3))) void*       las_p;

        const float* xb = x + (size_t)b * (CH * HH * WW) + (size_t)(i * 8u) * WW;

        // stage: slot s -> row r = s/34 (c = r/16, di = r%16), f4 k = s%34,
        // col = jq*128 + 4k (clamped to 508 for the jq=3 tail; pad slots
        // clamp r to 47 -- harmless dup loads, never read back).
#pragma unroll
        for (unsigned it = 0; it < 7; ++it) {
            unsigned s  = it * 256u + tid;             // [0, 1792)
            unsigned se = s < (SLOTS - 1) ? s : (SLOTS - 1);
            unsigned r  = se / ROWF4;                  // 0..47
            unsigned k  = se - r * ROWF4;              // 0..33
            unsigned col = jq * 128u + (k << 2);
            col = col < 508u ? col : 508u;
            const float* src = xb + ((size_t)(r >> 4) * (HH * WW))  // channel
                                  + (size_t)(r & 15u) * WW + col;
            __builtin_amdgcn_global_load_lds((gas_p)(const void*)src,
                                             (las_p)(void*)(lds + s * 4u),
                                             16, 0, 0);
        }
        __syncthreads();   // vmcnt(0) drain + barrier

        // write: slot t in [0, npat*192) f4s; p = t/192, f4i = t%192;
        // c = f4i>>6, di = (f4i>>2)&15, dj = (f4i&3)<<2.
        unsigned npat   = (jq == 3) ? 15u : 16u;
        unsigned nslots = npat * 192u;
        float* obase = out + (size_t)(b * NN + i * NW + jq * 16u) * FDIM;
#pragma unroll
        for (unsigned it = 0; it < 12; ++it) {
            unsigned t = it * 256u + tid;
            if (t < nslots) {
                unsigned p   = t / 192u;
                unsigned f4i = t - p * 192u;
                unsigned c   = f4i >> 6;
                unsigned di  = (f4i >> 2) & 15u;
                unsigned dj  = (f4i & 3u) << 2;
                const f4 v = *reinterpret_cast<const f4*>(
                    lds + ((c * 16u + di) * 136u + p * 8u + dj));
                __builtin_nontemporal_store(
                    v, reinterpret_cast<f4*>(obase + (size_t)t * 4));
            }
        }
    } else {
        unsigned g = bid * 256u + threadIdx.x;
        if (g >= PE_THREADS) return;
        unsigned n = g % NN;                // lanes contiguous in n
        unsigned b = g / NN;
        int i = (int)(n / NW);
        int j = (int)(n - (unsigned)i * NW);

        // positions
        *reinterpret_cast<f2*>(out + PATCHES_ELEMS + (size_t)(b * NN + n) * 2) =
            f2{(float)i, (float)j};

        // 8-NN on the 63x63 grid: the 9 best (incl. self) of top_k(-d2, 9)
        // always lie in the clipped 5x5 window; key = (d2<<12)|idx reproduces
        // top_k's exact ordering (ties -> lower index).
        unsigned best[9];
#pragma unroll
        for (int s = 0; s < 9; ++s) best[s] = 0xFFFFFFFFu;
        for (int di = -2; di <= 2; ++di) {
            int ni = i + di;
            if (ni < 0 || ni >= NH) continue;
            for (int dj = -2; dj <= 2; ++dj) {
                int nj = j + dj;
                if (nj < 0 || nj >= NW) continue;
                unsigned key = ((unsigned)(di * di + dj * dj) << 12)
                             | (unsigned)(ni * NW + nj);
#pragma unroll
                for (int s = 0; s < 9; ++s) {
                    if (key < best[s]) { unsigned tmp = best[s]; best[s] = key; key = tmp; }
                }
            }
        }

        float src_f = (float)n;
        f4 s4 = {src_f, src_f, src_f, src_f};
        f4 t0 = {(float)(best[1] & 0xFFFu), (float)(best[2] & 0xFFFu),
                 (float)(best[3] & 0xFFFu), (float)(best[4] & 0xFFFu)};
        f4 t1 = {(float)(best[5] & 0xFFFu), (float)(best[6] & 0xFFFu),
                 (float)(best[7] & 0xFFFu), (float)(best[8] & 0xFFFu)};

        float* ebase = out + PATCHES_ELEMS + POS_ELEMS + (size_t)b * 2 * EDGES;
        *reinterpret_cast<f4*>(ebase + (size_t)n * 8)             = s4;
        *reinterpret_cast<f4*>(ebase + (size_t)n * 8 + 4)         = s4;
        *reinterpret_cast<f4*>(ebase + EDGES + (size_t)n * 8)     = t0;
        *reinterpret_cast<f4*>(ebase + EDGES + (size_t)n * 8 + 4) = t1;
    }
}

extern "C" void kernel_launch(void* const* d_in, const int* in_sizes, int n_in,
                              void* d_out, int out_size, void* d_ws, size_t ws_size,
                              hipStream_t stream) {
    const float* x = (const float*)d_in[0];
    float* out     = (float*)d_out;
    fused_kernel<<<PE_BLOCKS + PATCH_BLOCKS, 256, 0, stream>>>(x, out);
}